// Round 3
// baseline (3672.529 us; speedup 1.0000x reference)
//
// MANN/NTM forward — R12: R11 + fix Wro_s init (800 elems needs strided loop,
// plain `if (tid<800)` with 512 threads left Wro_s[512..799] = LDS garbage).
// Structure: NBAT=1, 256 blocks (all CUs), k-split GEMVs across all waves so
// each SIMD carries 2 working waves (TLP hides GEMV load latency).
#include <hip/hip_runtime.h>
#include <math.h>

#define TB   100
#define BB   256
#define INF_ 784
#define HH   200
#define RR   4
#define NN   128
#define DD   40
#define NCLS 5
#define G4H  800   // 4*H
#define KAW  324   // 160 key + 160 add + 1 sigma + 3 pad
#define MST  44    // padded M row stride

__device__ __forceinline__ float sigmoidf_(float x) { return 1.0f / (1.0f + expf(-x)); }

// ---------------------------------------------------------------------------
// Prep: transpose weights into GEMV-friendly (k-major) layouts in workspace.
// ---------------------------------------------------------------------------
__global__ __launch_bounds__(256) void prep_kernel(
    const float* __restrict__ Whh, const float* __restrict__ Wrh,
    const float* __restrict__ Wkey, const float* __restrict__ Wadd,
    const float* __restrict__ Wsig, const float* __restrict__ bkey,
    const float* __restrict__ badd, const float* __restrict__ bsig,
    float* __restrict__ WhhT, float* __restrict__ WrhT,
    float* __restrict__ WkaT, float* __restrict__ bka)
{
  const int tid = blockIdx.x * 256 + threadIdx.x;
  if (tid < 160000) {            // Whh (800,200) -> WhhT (200,800)
    const int j = tid / 200, k = tid - j * 200;
    WhhT[k * G4H + j] = Whh[tid];
  }
  if (tid < 32000) {             // Wrh (200,160) -> WrhT (160,200)
    const int k = tid / 160, m = tid - k * 160;
    WrhT[m * HH + k] = Wrh[tid];
  }
  if (tid < 200 * KAW) {         // [Wkey(160,200)|Wadd(160,200)|Wsig(1,200)]^T
    const int k = tid / KAW, j = tid - k * KAW;
    float v = 0.0f;
    if (j < 160)       v = Wkey[j * HH + k];
    else if (j < 320)  v = Wadd[(j - 160) * HH + k];
    else if (j == 320) v = Wsig[k];
    WkaT[tid] = v;
  }
  if (tid < KAW) {
    float v = 0.0f;
    if (tid < 160)       v = bkey[tid];
    else if (tid < 320)  v = badd[tid - 160];
    else if (tid == 320) v = bsig[0];
    bka[tid] = v;
  }
}

// ---------------------------------------------------------------------------
// Big GEMM: G[m, j] = sum_k x[m,k]*Wih[j,k] + bih[j] + bhh[j]
// ---------------------------------------------------------------------------
__global__ __launch_bounds__(256) void gemm_in_kernel(
    const float* __restrict__ X, const float* __restrict__ Wih,
    const float* __restrict__ bih, const float* __restrict__ bhh,
    float* __restrict__ G)
{
  __shared__ float As[16 * 68];
  __shared__ float Bs[16 * 68];
  const int tid  = threadIdx.x;
  const int tx   = tid & 15, ty = tid >> 4;
  const int lrow = tid >> 2, lk = (tid & 3) * 4;
  const int n0 = blockIdx.x * 64;
  const int m0 = blockIdx.y * 64;
  const int jg = n0 + lrow;
  const float* Xp = X   + (size_t)(m0 + lrow) * INF_ + lk;
  const float* Wp = Wih + (size_t)jg * INF_ + lk;

  float acc[4][4];
#pragma unroll
  for (int i = 0; i < 4; ++i)
#pragma unroll
    for (int j = 0; j < 4; ++j) acc[i][j] = 0.f;

  for (int k0 = 0; k0 < INF_; k0 += 16) {
    const float4 a = *(const float4*)(Xp + k0);
    const float4 b = (jg < G4H) ? *(const float4*)(Wp + k0)
                                : make_float4(0.f, 0.f, 0.f, 0.f);
    __syncthreads();
    const float av[4] = {a.x, a.y, a.z, a.w};
    const float bv[4] = {b.x, b.y, b.z, b.w};
#pragma unroll
    for (int u = 0; u < 4; ++u) {
      As[(lk + u) * 68 + lrow] = av[u];
      Bs[(lk + u) * 68 + lrow] = bv[u];
    }
    __syncthreads();
#pragma unroll
    for (int k = 0; k < 16; ++k) {
      const float4 a4 = *(const float4*)&As[k * 68 + ty * 4];
      const float4 b4 = *(const float4*)&Bs[k * 68 + tx * 4];
      const float aa[4] = {a4.x, a4.y, a4.z, a4.w};
      const float bb[4] = {b4.x, b4.y, b4.z, b4.w};
#pragma unroll
      for (int i = 0; i < 4; ++i)
#pragma unroll
        for (int j = 0; j < 4; ++j) acc[i][j] += aa[i] * bb[j];
    }
  }
  const int jc = n0 + tx * 4;
  if (jc < G4H) {
    float bs[4];
#pragma unroll
    for (int u = 0; u < 4; ++u) bs[u] = bih[jc + u] + bhh[jc + u];
#pragma unroll
    for (int i = 0; i < 4; ++i) {
      const size_t m = (size_t)m0 + ty * 4 + i;
      const float4 v = make_float4(acc[i][0] + bs[0], acc[i][1] + bs[1],
                                   acc[i][2] + bs[2], acc[i][3] + bs[3]);
      *(float4*)(G + m * G4H + jc) = v;
    }
  }
}

// ---------------------------------------------------------------------------
// Recurrence: one block (512 thr) per batch element; 256 blocks = all CUs.
// Every GEMV is k-split across lanes so >=6 of 8 waves work (2 waves/SIMD TLP).
// ---------------------------------------------------------------------------

// load 10 consecutive-k float4 weights (stride S float4 between k rows)
#define LD10(BUF, C, W, S) { _Pragma("unroll") \
  for (int u = 0; u < 10; ++u) BUF[u] = (W)[((C) * 10 + u) * (S)]; }
// fma 10 k-steps against broadcast vector V (LDS), base index KB
#define FM10(BUF, C, KB, V, ACC) { _Pragma("unroll") \
  for (int u = 0; u < 10; ++u) { const float hk = (V)[(KB) + (C) * 10 + u]; \
    ACC.x += hk * BUF[u].x; ACC.y += hk * BUF[u].y; \
    ACC.z += hk * BUF[u].z; ACC.w += hk * BUF[u].w; } }

__global__ __launch_bounds__(512) void mann_kernel(
    const float* __restrict__ G, const float* __restrict__ WhhT,
    const float* __restrict__ WrhT, const float* __restrict__ WkaT,
    const float* __restrict__ bka, const float* __restrict__ brh,
    const float* __restrict__ Who, const float* __restrict__ bho,
    const float* __restrict__ Wro, const float* __restrict__ bro,
    float* __restrict__ out)
{
  __shared__ __attribute__((aligned(16))) float M_s[NN * MST];      // 5632
  __shared__ __attribute__((aligned(16))) float h_s[HH];
  __shared__ __attribute__((aligned(16))) float c_s[HH];
  __shared__ __attribute__((aligned(16))) float r_s[RR * DD];
  __shared__ __attribute__((aligned(16))) float brh_s[HH];
  __shared__ float wr_s[RR * NN];
  __shared__ float ww_s[RR * NN];
  __shared__ float wu_s[NN];
  __shared__ float Mn2p[2][NN];
  __shared__ float kn2_s[RR];
  __shared__ __attribute__((aligned(16))) float gates_s[G4H];       // alias Kp
  __shared__ __attribute__((aligned(16))) float ka_s[KAW];
  __shared__ __attribute__((aligned(16))) float bka_s[KAW];
  __shared__ __attribute__((aligned(16))) float Gbuf_s[2][G4H];
  __shared__ __attribute__((aligned(16))) float scr_s[1600];        // partials
  __shared__ float Who_s[NCLS * HH], Wro_s[NCLS * RR * DD], bo_s[NCLS];
  __shared__ int   lu_s[RR];

  float* Kp = gates_s;   // wr_t lives here P8..end (512 floats)

  const int tid = threadIdx.x;
  const int b   = blockIdx.x;

  // ---- init ----
  for (int e = tid; e < NN * MST; e += 512) M_s[e] = 0.f;
  if (tid < RR * NN) wr_s[tid] = 0.f;
  if (tid < NN) wu_s[tid] = 0.f;
  if (tid < HH) { h_s[tid] = 0.f; c_s[tid] = 0.f; brh_s[tid] = brh[tid]; }
  if (tid < RR * DD) r_s[tid] = 0.f;
  if (tid < KAW) bka_s[tid] = bka[tid];
  for (int e = tid; e < NCLS * HH; e += 512) Who_s[e] = Who[e];
  for (int e = tid; e < NCLS * RR * DD; e += 512) Wro_s[e] = Wro[e];  // R12 fix
  if (tid < NCLS) bo_s[tid] = bho[tid] + bro[tid];
  if (tid < 200)
    ((float4*)&Gbuf_s[0][0])[tid] =
        ((const float4*)(G + (size_t)b * TB * G4H))[tid];
  __syncthreads();

#pragma clang loop unroll(disable)
  for (int t = 0; t < TB; ++t) {
    // ---- P1a: partial h-increment: 400 lanes = 50 j4 x 8 k-splits (20 k) ----
    if (tid < 400) {
      const int kh = tid / 50, j4 = tid - kh * 50;
      const int kb = kh * 20;
      const float4* __restrict__ W = (const float4*)WrhT + (size_t)kb * 50 + j4;
      float4 acc = make_float4(0.f, 0.f, 0.f, 0.f);
      float4 wa[10], wb[10];
      LD10(wa, 0, W, 50) LD10(wb, 1, W, 50)
      FM10(wa, 0, kb, r_s, acc) FM10(wb, 1, kb, r_s, acc)
      ((float4*)scr_s)[kh * 50 + j4] = acc;   // 400 float4
    }
    __syncthreads();
    // ---- P1b: finalize h (50 lanes) ----
    if (tid < 50) {
      float4 s = make_float4(0.f, 0.f, 0.f, 0.f);
#pragma unroll
      for (int kh = 0; kh < 8; ++kh) {
        const float4 p = ((const float4*)scr_s)[kh * 50 + tid];
        s.x += p.x; s.y += p.y; s.z += p.z; s.w += p.w;
      }
      float4 hv = *(const float4*)&h_s[4 * tid];
      const float4 brv = *(const float4*)&brh_s[4 * tid];
      hv.x += s.x + brv.x; hv.y += s.y + brv.y;
      hv.z += s.z + brv.z; hv.w += s.w + brv.w;
      *(float4*)&h_s[4 * tid] = hv;
    }
    __syncthreads();

    // ---- P2a: gates partial: 400 lanes = 200 j4 x 2 k-halves (100 k);
    //      wave 7 prefetches G(t+1) into alternate Gbuf slot ----
    if (tid < 400) {
      const int kh = tid / 200, j4 = tid - kh * 200;
      const int kb = kh * 100;
      const float4* __restrict__ W = (const float4*)WhhT + (size_t)kb * 200 + j4;
      float4 acc = make_float4(0.f, 0.f, 0.f, 0.f);
      float4 wa[10], wb[10];
      LD10(wa, 0, W, 200) LD10(wb, 1, W, 200)
      FM10(wa, 0, kb, h_s, acc) LD10(wa, 2, W, 200)
      FM10(wb, 1, kb, h_s, acc) LD10(wb, 3, W, 200)
      FM10(wa, 2, kb, h_s, acc) LD10(wa, 4, W, 200)
      FM10(wb, 3, kb, h_s, acc) LD10(wb, 5, W, 200)
      FM10(wa, 4, kb, h_s, acc) LD10(wa, 6, W, 200)
      FM10(wb, 5, kb, h_s, acc) LD10(wb, 7, W, 200)
      FM10(wa, 6, kb, h_s, acc) LD10(wa, 8, W, 200)
      FM10(wb, 7, kb, h_s, acc) LD10(wb, 9, W, 200)
      FM10(wa, 8, kb, h_s, acc)
      FM10(wb, 9, kb, h_s, acc)
      ((float4*)scr_s)[kh * 200 + j4] = acc;  // 400 float4
    } else if (tid >= 448 && t + 1 < TB) {
      for (int o = tid - 448; o < 200; o += 64)
        ((float4*)&Gbuf_s[(t + 1) & 1][0])[o] =
            ((const float4*)(G + ((size_t)b * TB + t + 1) * G4H))[o];
    }
    __syncthreads();
    // ---- P2b: finalize gates (200 lanes) ----
    if (tid < 200) {
      float4 g = ((const float4*)&Gbuf_s[t & 1][0])[tid];
      const float4 p0 = ((const float4*)scr_s)[tid];
      const float4 p1 = ((const float4*)scr_s)[200 + tid];
      g.x += p0.x + p1.x; g.y += p0.y + p1.y;
      g.z += p0.z + p1.z; g.w += p0.w + p1.w;
      ((float4*)gates_s)[tid] = g;
    }
    __syncthreads();

    // ---- P3: LSTM pointwise (200 lanes) ----
    if (tid < HH) {
      const float ig = sigmoidf_(gates_s[tid]);
      const float fg = sigmoidf_(gates_s[HH + tid]);
      const float gg = tanhf(gates_s[2 * HH + tid]);
      const float og = sigmoidf_(gates_s[3 * HH + tid]);
      const float cn = fg * c_s[tid] + ig * gg;
      c_s[tid] = cn;
      h_s[tid] = og * tanhf(cn);
    }
    __syncthreads();

    // ---- P4a: [key|add|sigma] partial: 324 lanes = 81 j4 x 4 k-splits (50 k) ----
    if (tid < 324) {
      const int kh = tid / 81, j4 = tid - kh * 81;
      const int kb = kh * 50;
      const float4* __restrict__ W = (const float4*)WkaT + (size_t)kb * 81 + j4;
      float4 acc = make_float4(0.f, 0.f, 0.f, 0.f);
      float4 wa[10], wb[10];
      LD10(wa, 0, W, 81) LD10(wb, 1, W, 81)
      FM10(wa, 0, kb, h_s, acc) LD10(wa, 2, W, 81)
      FM10(wb, 1, kb, h_s, acc) LD10(wb, 3, W, 81)
      FM10(wa, 2, kb, h_s, acc) LD10(wa, 4, W, 81)
      FM10(wb, 3, kb, h_s, acc)
      FM10(wa, 4, kb, h_s, acc)
      ((float4*)scr_s)[kh * 81 + j4] = acc;   // 324 float4
    }
    __syncthreads();
    // ---- P4b: finalize ka (81 lanes) ----
    if (tid < 81) {
      float4 v = ((const float4*)bka_s)[tid];
#pragma unroll
      for (int kh = 0; kh < 4; ++kh) {
        const float4 p = ((const float4*)scr_s)[kh * 81 + tid];
        v.x += p.x; v.y += p.y; v.z += p.z; v.w += p.w;
      }
      ((float4*)ka_s)[tid] = v;
    }
    __syncthreads();

    // ---- P5: least-used select (wave 0) + key norms (lanes 64-67) ----
    if (tid < 64) {
      const int l = tid;
      unsigned u0v = __float_as_uint(wu_s[l]);
      unsigned u1v = __float_as_uint(wu_s[l + 64]);
      if (u0v == 0x80000000u) u0v = 0u;
      if (u1v == 0x80000000u) u1v = 0u;
      u0v = (u0v & 0x80000000u) ? ~u0v : (u0v | 0x80000000u);
      u1v = (u1v & 0x80000000u) ? ~u1v : (u1v | 0x80000000u);
      unsigned long long k0 = ((unsigned long long)u0v << 32) | (unsigned)l;
      unsigned long long k1 = ((unsigned long long)u1v << 32) | (unsigned)(l + 64);
#pragma unroll
      for (int rsel = 0; rsel < RR; ++rsel) {
        unsigned long long mn = (k0 < k1) ? k0 : k1;
#pragma unroll
        for (int off = 32; off; off >>= 1) {
          const unsigned long long o = __shfl_xor(mn, off);
          if (o < mn) mn = o;
        }
        const int idx = (int)(mn & 0xFFFFFFFFull);
        if (l == 0) lu_s[rsel] = idx;
        if (idx == l)      k0 = ~0ull;
        if (idx == l + 64) k1 = ~0ull;
      }
    } else if (tid < 68) {
      const int q = tid - 64;
      float s = 0.f;
#pragma unroll
      for (int d4 = 0; d4 < 10; ++d4) {
        const float4 v = *(const float4*)&ka_s[q * DD + 4 * d4];
        s += v.x * v.x + v.y * v.y + v.z * v.z + v.w * v.w;
      }
      kn2_s[q] = s;
    }
    __syncthreads();

    // ---- P6: ww = sigma*wr + (1-sigma)*wlu (128 lanes) ----
    if (tid < NN) {
      const float sg = ka_s[320];
      const int l0 = lu_s[0], l1 = lu_s[1], l2 = lu_s[2], l3 = lu_s[3];
      const float wlu = (tid == l0 || tid == l1 || tid == l2 || tid == l3) ? 1.f : 0.f;
#pragma unroll
      for (int q = 0; q < RR; ++q)
        ww_s[q * NN + tid] = sg * wr_s[q * NN + tid] + (1.f - sg) * wlu;
    }
    __syncthreads();

    // ---- P7: M update + row-norm partials (256 lanes = 128 n x 2 d-halves) ----
    if (tid < 256) {
      const int dh = tid >> 7, n = tid & (NN - 1);
      const int l0 = lu_s[0], l1 = lu_s[1], l2 = lu_s[2], l3 = lu_s[3];
      const float wlu = (n == l0 || n == l1 || n == l2 || n == l3) ? 1.f : 0.f;
      const float wwv0 = ww_s[n],          wwv1 = ww_s[NN + n];
      const float wwv2 = ww_s[2 * NN + n], wwv3 = ww_s[3 * NN + n];
      float* Mr = &M_s[n * MST + dh * 20];
      const float* Ad = &ka_s[160 + dh * 20];
      float mn2 = 0.f;
#pragma unroll
      for (int d4 = 0; d4 < 5; ++d4) {
        float4 m = *(const float4*)&Mr[4 * d4];
        m.x *= wlu; m.y *= wlu; m.z *= wlu; m.w *= wlu;
        const float4 av0 = *(const float4*)&Ad[0 * DD + 4 * d4];
        const float4 av1 = *(const float4*)&Ad[1 * DD + 4 * d4];
        const float4 av2 = *(const float4*)&Ad[2 * DD + 4 * d4];
        const float4 av3 = *(const float4*)&Ad[3 * DD + 4 * d4];
        m.x += wwv0 * av0.x + wwv1 * av1.x + wwv2 * av2.x + wwv3 * av3.x;
        m.y += wwv0 * av0.y + wwv1 * av1.y + wwv2 * av2.y + wwv3 * av3.y;
        m.z += wwv0 * av0.z + wwv1 * av1.z + wwv2 * av2.z + wwv3 * av3.z;
        m.w += wwv0 * av0.w + wwv1 * av1.w + wwv2 * av2.w + wwv3 * av3.w;
        *(float4*)&Mr[4 * d4] = m;
        mn2 += m.x * m.x + m.y * m.y + m.z * m.z + m.w * m.w;
      }
      Mn2p[dh][n] = mn2;
    }
    __syncthreads();

    // ---- P8: K = cosine(key, M): 512 lanes = 4 keys x 128 rows ----
    {
      const int q = tid >> 7, n = tid & (NN - 1);
      const float* Mr = &M_s[n * MST];
      const float* Ky = &ka_s[q * DD];
      float s = 0.f;
#pragma unroll
      for (int d4 = 0; d4 < 10; ++d4) {
        const float4 mv = *(const float4*)&Mr[4 * d4];
        const float4 kv = *(const float4*)&Ky[4 * d4];
        s += kv.x * mv.x + kv.y * mv.y + kv.z * mv.z + kv.w * mv.w;
      }
      const float mn2 = Mn2p[0][n] + Mn2p[1][n];
      Kp[q * NN + n] = s / sqrtf(kn2_s[q] * mn2 + 1e-6f);
    }
    __syncthreads();

    // ---- P9: softmax over N (4 rows, one per wave; waves 4-7 idle) ----
    {
      const int w = tid >> 6, l = tid & 63;
      if (w < 4) {
        float* Kr = Kp + w * NN;
        const float v0 = Kr[l], v1 = Kr[l + 64];
        float mx = fmaxf(v0, v1);
#pragma unroll
        for (int off = 32; off; off >>= 1) mx = fmaxf(mx, __shfl_xor(mx, off));
        const float e0 = expf(v0 - mx), e1 = expf(v1 - mx);
        float s = e0 + e1;
#pragma unroll
        for (int off = 32; off; off >>= 1) s += __shfl_xor(s, off);
        const float inv = 1.f / s;
        Kr[l] = e0 * inv; Kr[l + 64] = e1 * inv;
      }
    }
    __syncthreads();

    // ---- P10: r = wr_t @ M (320 lanes, 8-lane shfl reduce) ;
    //      P11: wu update (lanes 320-447) ; wr <- wr_t (lanes 448+) ----
    if (tid < 320) {
      const int g = tid >> 3, ns = tid & 7;     // g = q*10+d4
      const int q = g / 10, d4 = g - q * 10;
      const float* Kr = Kp + q * NN;
      const float* Mb = &M_s[4 * d4];
      float4 acc = make_float4(0.f, 0.f, 0.f, 0.f);
#pragma unroll
      for (int j = 0; j < 16; ++j) {
        const int n = ns + 8 * j;               // bank-spread over ns
        const float kw = Kr[n];
        const float4 mv = *(const float4*)&Mb[n * MST];
        acc.x += kw * mv.x; acc.y += kw * mv.y;
        acc.z += kw * mv.z; acc.w += kw * mv.w;
      }
#pragma unroll
      for (int off = 4; off; off >>= 1) {
        acc.x += __shfl_xor(acc.x, off);
        acc.y += __shfl_xor(acc.y, off);
        acc.z += __shfl_xor(acc.z, off);
        acc.w += __shfl_xor(acc.w, off);
      }
      if (ns == 0) *(float4*)&r_s[q * DD + 4 * d4] = acc;
    } else if (tid < 448) {
      const int n = tid - 320;
      float s = 0.95f * wu_s[n];
#pragma unroll
      for (int q = 0; q < RR; ++q)
        s += Kp[q * NN + n] + ww_s[q * NN + n];
      wu_s[n] = s;
    } else {
      for (int f = tid - 448; f < RR * NN; f += 64) wr_s[f] = Kp[f];
    }
    __syncthreads();

    // ---- P12: out (wave 0) ----
    if (tid < 64) {
      const size_t ob = ((size_t)b * TB + t) * NCLS;
#pragma unroll
      for (int j = 0; j < NCLS; ++j) {
        float p = 0.f;
        for (int k = tid; k < HH; k += 64)      p += h_s[k] * Who_s[j * HH + k];
        for (int m = tid; m < RR * DD; m += 64) p += r_s[m] * Wro_s[j * RR * DD + m];
#pragma unroll
        for (int off = 32; off; off >>= 1) p += __shfl_xor(p, off);
        if (tid == 0) out[ob + j] = p + bo_s[j];
      }
    }
    __syncthreads();
  }
}

// ---------------------------------------------------------------------------
extern "C" void kernel_launch(void* const* d_in, const int* in_sizes, int n_in,
                              void* d_out, int out_size, void* d_ws, size_t ws_size,
                              hipStream_t stream) {
  const float* x    = (const float*)d_in[0];
  const float* Wkey = (const float*)d_in[1];
  const float* bkey = (const float*)d_in[2];
  const float* Wadd = (const float*)d_in[3];
  const float* badd = (const float*)d_in[4];
  const float* Wsig = (const float*)d_in[5];
  const float* bsig = (const float*)d_in[6];
  const float* Who  = (const float*)d_in[7];
  const float* bho  = (const float*)d_in[8];
  const float* Wro  = (const float*)d_in[9];
  const float* bro  = (const float*)d_in[10];
  const float* Wrh  = (const float*)d_in[11];
  const float* brh  = (const float*)d_in[12];
  const float* Wih  = (const float*)d_in[13];
  const float* bih  = (const float*)d_in[14];
  const float* Whh  = (const float*)d_in[15];
  const float* bhh  = (const float*)d_in[16];

  float* ws   = (float*)d_ws;
  float* G    = ws;                       // 25600*800
  float* WhhT = G + (size_t)25600 * 800;  // 160,000
  float* WrhT = WhhT + 160000;            // 32,000
  float* WkaT = WrhT + 32000;             // 64,800
  float* bka  = WkaT + 64800;             // 324

  prep_kernel<<<(160000 + 255) / 256, 256, 0, stream>>>(
      Whh, Wrh, Wkey, Wadd, Wsig, bkey, badd, bsig, WhhT, WrhT, WkaT, bka);

  dim3 gA((G4H + 63) / 64, 25600 / 64);
  gemm_in_kernel<<<gA, 256, 0, stream>>>(x, Wih, bih, bhh, G);

  mann_kernel<<<BB, 512, 0, stream>>>(G, WhhT, WrhT, WkaT, bka, brh,
                                      Who, bho, Wro, bro, (float*)d_out);
}